// Round 1
// baseline (967.410 us; speedup 1.0000x reference)
//
#include <hip/hip_runtime.h>
#include <hip/hip_bf16.h>

// Problem dims (fixed by reference)
#define L_DIM 2048
#define B_DIM 16
#define NIN   1024
#define NOUT  1024
#define M_DIM (L_DIM * B_DIM)   // 32768 GEMM rows (l*B+b)
#define N_DIM (2 * NOUT)        // 2048 GEMM cols (interleaved gates)
#define K_DIM NIN               // 1024

typedef __bf16 bf16x8 __attribute__((ext_vector_type(8)));
typedef float  f32x4  __attribute__((ext_vector_type(4)));
typedef unsigned short us4 __attribute__((ext_vector_type(4)));

// fp32 -> bf16 round-to-nearest-even (inputs are finite; no NaN path needed)
__device__ __forceinline__ unsigned short f2bf(float f) {
    unsigned int u = __float_as_uint(f);
    unsigned int r = (u + 0x7fffu + ((u >> 16) & 1u)) >> 16;
    return (unsigned short)r;
}

// ---------------- input fp32 -> bf16, elementwise (coalesced float4) --------
__global__ void cvt_input_kernel(const float* __restrict__ in,
                                 unsigned short* __restrict__ out) {
    size_t i = ((size_t)blockIdx.x * 256 + threadIdx.x) * 4;
    float4 v = *(const float4*)(in + i);
    us4 o = { f2bf(v.x), f2bf(v.y), f2bf(v.z), f2bf(v.w) };
    *(us4*)(out + i) = o;
}

// ------------- weight fp32 [K][N] -> bf16 transposed [N][K] (LDS tile) ------
__global__ void cvt_weight_kernel(const float* __restrict__ W,
                                  unsigned short* __restrict__ Wt) {
    __shared__ float t[32][33];
    int tx = threadIdx.x, ty = threadIdx.y;           // 32 x 8
    int i0 = blockIdx.y * 32, n0 = blockIdx.x * 32;
    #pragma unroll
    for (int r = 0; r < 4; ++r)
        t[ty + r * 8][tx] = W[(size_t)(i0 + ty + r * 8) * N_DIM + n0 + tx];
    __syncthreads();
    #pragma unroll
    for (int r = 0; r < 4; ++r)
        Wt[(size_t)(n0 + ty + r * 8) * K_DIM + i0 + tx] = f2bf(t[tx][ty + r * 8]);
}

// ---------------- bf16 MFMA GEMM + fused gate epilogue ----------------------
// C[m, 2o]   -> u0   = u_even * (1 - sigmoid(u_odd + bias[NOUT+o]))  -> u0buf
// C[m, 2o+1] -> fgate = sigmoid(u_odd + bias[NOUT+o])                -> fbuf
#define BM 128
#define BN 128
#define BK 32
#define LDAS 40   // padded LDS pitch in ushorts (80 B: 16B-aligned, conflict-light)

template<bool PRE_A>
__global__ void gemm_kernel(const float* __restrict__ A32,
                            const unsigned short* __restrict__ Abf,
                            const unsigned short* __restrict__ Wt,
                            const float* __restrict__ bias,
                            float* __restrict__ u0buf,
                            float* __restrict__ fbuf) {
    __shared__ unsigned short As[BM * LDAS];
    __shared__ unsigned short Bs[BN * LDAS];
    __shared__ float sFB[64];

    const int tid = threadIdx.x;
    const int bm = blockIdx.y * BM;
    const int bn = blockIdx.x * BN;
    const int obase = bn >> 1;

    if (tid < 64) sFB[tid] = bias[NOUT + obase + tid];

    const int lane = tid & 63;
    const int wave = tid >> 6;
    const int wr = wave >> 1;          // 2x2 wave grid, 64x64 per wave
    const int wc = wave & 1;
    const int mrow = lane & 15;        // A row / B col within 16-tile
    const int kq = (lane >> 4) * 8;    // k offset within BK=32

    f32x4 acc[4][4];
    #pragma unroll
    for (int i = 0; i < 4; ++i)
        #pragma unroll
        for (int j = 0; j < 4; ++j)
            acc[i][j] = (f32x4){0.f, 0.f, 0.f, 0.f};

    for (int k0 = 0; k0 < K_DIM; k0 += BK) {
        // ---- stage A tile (BM x BK) ----
        if (PRE_A) {
            #pragma unroll
            for (int r = 0; r < 2; ++r) {
                int idx = tid + r * 256;
                int row = idx >> 2;
                int kc  = (idx & 3) << 3;
                *(uint4*)&As[row * LDAS + kc] =
                    *(const uint4*)&Abf[(size_t)(bm + row) * K_DIM + k0 + kc];
            }
        } else {
            #pragma unroll
            for (int r = 0; r < 4; ++r) {
                int idx = tid + r * 256;
                int row = idx >> 3;
                int kc  = (idx & 7) << 2;
                float4 v = *(const float4*)&A32[(size_t)(bm + row) * K_DIM + k0 + kc];
                us4 o = { f2bf(v.x), f2bf(v.y), f2bf(v.z), f2bf(v.w) };
                *(us4*)&As[row * LDAS + kc] = o;
            }
        }
        // ---- stage B tile (BN x BK) from K-major Wt ----
        #pragma unroll
        for (int r = 0; r < 2; ++r) {
            int idx = tid + r * 256;
            int row = idx >> 2;
            int kc  = (idx & 3) << 3;
            *(uint4*)&Bs[row * LDAS + kc] =
                *(const uint4*)&Wt[(size_t)(bn + row) * K_DIM + k0 + kc];
        }
        __syncthreads();

        bf16x8 a[4], b[4];
        #pragma unroll
        for (int mt = 0; mt < 4; ++mt)
            a[mt] = *(const bf16x8*)&As[(wr * 64 + mt * 16 + mrow) * LDAS + kq];
        #pragma unroll
        for (int nt = 0; nt < 4; ++nt)
            b[nt] = *(const bf16x8*)&Bs[(wc * 64 + nt * 16 + mrow) * LDAS + kq];
        #pragma unroll
        for (int mt = 0; mt < 4; ++mt)
            #pragma unroll
            for (int nt = 0; nt < 4; ++nt)
                acc[mt][nt] = __builtin_amdgcn_mfma_f32_16x16x32_bf16(
                    a[mt], b[nt], acc[mt][nt], 0, 0, 0);
        __syncthreads();
    }

    // ---- epilogue: pair even/odd columns via shfl_xor(1); lane parity == col parity
    const bool isOdd = (mrow & 1);
    #pragma unroll
    for (int mt = 0; mt < 4; ++mt) {
        #pragma unroll
        for (int nt = 0; nt < 4; ++nt) {
            int gcol = bn + wc * 64 + nt * 16 + mrow;
            int o = gcol >> 1;
            float fb = sFB[o - obase];
            #pragma unroll
            for (int r = 0; r < 4; ++r) {
                float x = acc[mt][nt][r];
                float p = __shfl_xor(x, 1, 64);            // partner column's value
                float uo = isOdd ? x : p;                  // the odd-gate pre-act
                float f = 1.f / (1.f + __expf(-(uo + fb)));
                int grow = bm + wr * 64 + mt * 16 + (lane >> 4) * 4 + r;
                size_t oi = (size_t)grow * NOUT + o;
                if (isOdd) fbuf[oi]  = f;
                else       u0buf[oi] = x * (1.f - f);
            }
        }
    }
}

// ---------------- sequential scan: c_t = c_{t-1}*f_t + u_t, in-place --------
__global__ void scan_kernel(const float* __restrict__ fgate,
                            const float* __restrict__ c_init,
                            float* __restrict__ cs,      // holds u0 on entry
                            float* __restrict__ c_final) {
    int j = blockIdx.x * 256 + threadIdx.x;              // 0..16383 = b*1024+o
    float c = c_init[j];
    #pragma unroll 4
    for (int l = 0; l < L_DIM; ++l) {
        size_t idx = (size_t)l * (B_DIM * NOUT) + j;
        float ft = fgate[idx];
        float u  = cs[idx];
        c = fmaf(c, ft, u);
        cs[idx] = c;
    }
    c_final[j] = c;
}

extern "C" void kernel_launch(void* const* d_in, const int* in_sizes, int n_in,
                              void* d_out, int out_size, void* d_ws, size_t ws_size,
                              hipStream_t stream) {
    const float* input  = (const float*)d_in[0];  // [L,B,NIN]
    const float* c_init = (const float*)d_in[1];  // [B,NOUT]
    const float* weight = (const float*)d_in[2];  // [NIN, 2*NOUT]
    const float* bias   = (const float*)d_in[3];  // [2*NOUT]

    float* out_cs = (float*)d_out;                         // [L,B,NOUT]
    float* out_cf = out_cs + (size_t)L_DIM * B_DIM * NOUT; // [B,NOUT]
    float* out_fg = out_cf + (size_t)B_DIM * NOUT;         // [L,B,NOUT]

    // ws layout: [Wt bf16: N*K][Abf bf16: M*K] (Abf only if ws is big enough)
    size_t wt_bytes = (size_t)N_DIM * K_DIM * sizeof(unsigned short);  // 4 MB
    size_t wt_pad   = (wt_bytes + 255) & ~(size_t)255;
    size_t a_bytes  = (size_t)M_DIM * K_DIM * sizeof(unsigned short);  // 64 MB
    unsigned short* Wt  = (unsigned short*)d_ws;
    unsigned short* Abf = (unsigned short*)((char*)d_ws + wt_pad);
    bool pre_a = (ws_size >= wt_pad + a_bytes);

    // 1) weight fp32 [K][N] -> bf16 Wt [N][K]
    cvt_weight_kernel<<<dim3(N_DIM / 32, K_DIM / 32), dim3(32, 8), 0, stream>>>(weight, Wt);

    // 2) input fp32 -> bf16 (skippable fallback if ws too small)
    if (pre_a) {
        int nblk = (M_DIM * K_DIM) / (4 * 256);  // 32768
        cvt_input_kernel<<<nblk, 256, 0, stream>>>(input, Abf);
    }

    // 3) GEMM + gate epilogue: u0 -> out_cs (temp), forget -> out_fg
    dim3 ggrid(N_DIM / BN, M_DIM / BM);          // (16, 256)
    if (pre_a)
        gemm_kernel<true ><<<ggrid, 256, 0, stream>>>(input, Abf, Wt, bias, out_cs, out_fg);
    else
        gemm_kernel<false><<<ggrid, 256, 0, stream>>>(input, Abf, Wt, bias, out_cs, out_fg);

    // 4) recurrence, in-place on out_cs
    scan_kernel<<<(B_DIM * NOUT) / 256, 256, 0, stream>>>(out_fg, c_init, out_cs, out_cf);
}

// Round 2
// 667.956 us; speedup vs baseline: 1.4483x; 1.4483x over previous
//
#include <hip/hip_runtime.h>
#include <hip/hip_bf16.h>

// Problem dims (fixed by reference)
#define L_DIM 2048
#define B_DIM 16
#define NIN   1024
#define NOUT  1024
#define M_DIM (L_DIM * B_DIM)   // 32768 GEMM rows (l*B+b)
#define N_DIM (2 * NOUT)        // 2048 GEMM cols (interleaved gates)
#define K_DIM NIN               // 1024
#define NCOL  (B_DIM * NOUT)    // 16384 independent scan columns
#define NCH   64                // scan chunks over L
#define LC    (L_DIM / NCH)     // 32 steps per chunk

typedef __bf16 bf16x8 __attribute__((ext_vector_type(8)));
typedef float  f32x4  __attribute__((ext_vector_type(4)));
typedef unsigned short us4 __attribute__((ext_vector_type(4)));

// fp32 -> bf16 round-to-nearest-even (inputs are finite; no NaN path needed)
__device__ __forceinline__ unsigned short f2bf(float f) {
    unsigned int u = __float_as_uint(f);
    unsigned int r = (u + 0x7fffu + ((u >> 16) & 1u)) >> 16;
    return (unsigned short)r;
}

// ---------------- input fp32 -> bf16, elementwise (coalesced float4) --------
__global__ void cvt_input_kernel(const float* __restrict__ in,
                                 unsigned short* __restrict__ out) {
    size_t i = ((size_t)blockIdx.x * 256 + threadIdx.x) * 4;
    float4 v = *(const float4*)(in + i);
    us4 o = { f2bf(v.x), f2bf(v.y), f2bf(v.z), f2bf(v.w) };
    *(us4*)(out + i) = o;
}

// ------------- weight fp32 [K][N] -> bf16 transposed [N][K] (LDS tile) ------
__global__ void cvt_weight_kernel(const float* __restrict__ W,
                                  unsigned short* __restrict__ Wt) {
    __shared__ float t[32][33];
    int tx = threadIdx.x, ty = threadIdx.y;           // 32 x 8
    int i0 = blockIdx.y * 32, n0 = blockIdx.x * 32;
    #pragma unroll
    for (int r = 0; r < 4; ++r)
        t[ty + r * 8][tx] = W[(size_t)(i0 + ty + r * 8) * N_DIM + n0 + tx];
    __syncthreads();
    #pragma unroll
    for (int r = 0; r < 4; ++r)
        Wt[(size_t)(n0 + ty + r * 8) * K_DIM + i0 + tx] = f2bf(t[tx][ty + r * 8]);
}

// ---------------- bf16 MFMA GEMM + fused gate epilogue ----------------------
// C[m, 2o]   -> u0   = u_even * (1 - sigmoid(u_odd + bias[NOUT+o]))  -> u0buf
// C[m, 2o+1] -> fgate = sigmoid(u_odd + bias[NOUT+o])                -> fbuf
#define BM 128
#define BN 128
#define BK 32
#define LDAS 40   // padded LDS pitch in ushorts (80 B: 16B-aligned, conflict-light)

template<bool PRE_A>
__global__ void gemm_kernel(const float* __restrict__ A32,
                            const unsigned short* __restrict__ Abf,
                            const unsigned short* __restrict__ Wt,
                            const float* __restrict__ bias,
                            float* __restrict__ u0buf,
                            float* __restrict__ fbuf) {
    __shared__ unsigned short As[BM * LDAS];
    __shared__ unsigned short Bs[BN * LDAS];
    __shared__ float sFB[64];

    const int tid = threadIdx.x;
    const int bm = blockIdx.y * BM;
    const int bn = blockIdx.x * BN;
    const int obase = bn >> 1;

    if (tid < 64) sFB[tid] = bias[NOUT + obase + tid];

    const int lane = tid & 63;
    const int wave = tid >> 6;
    const int wr = wave >> 1;          // 2x2 wave grid, 64x64 per wave
    const int wc = wave & 1;
    const int mrow = lane & 15;        // A row / B col within 16-tile
    const int kq = (lane >> 4) * 8;    // k offset within BK=32

    f32x4 acc[4][4];
    #pragma unroll
    for (int i = 0; i < 4; ++i)
        #pragma unroll
        for (int j = 0; j < 4; ++j)
            acc[i][j] = (f32x4){0.f, 0.f, 0.f, 0.f};

    for (int k0 = 0; k0 < K_DIM; k0 += BK) {
        // ---- stage A tile (BM x BK) ----
        if (PRE_A) {
            #pragma unroll
            for (int r = 0; r < 2; ++r) {
                int idx = tid + r * 256;
                int row = idx >> 2;
                int kc  = (idx & 3) << 3;
                *(uint4*)&As[row * LDAS + kc] =
                    *(const uint4*)&Abf[(size_t)(bm + row) * K_DIM + k0 + kc];
            }
        } else {
            #pragma unroll
            for (int r = 0; r < 4; ++r) {
                int idx = tid + r * 256;
                int row = idx >> 3;
                int kc  = (idx & 7) << 2;
                float4 v = *(const float4*)&A32[(size_t)(bm + row) * K_DIM + k0 + kc];
                us4 o = { f2bf(v.x), f2bf(v.y), f2bf(v.z), f2bf(v.w) };
                *(us4*)&As[row * LDAS + kc] = o;
            }
        }
        // ---- stage B tile (BN x BK) from K-major Wt ----
        #pragma unroll
        for (int r = 0; r < 2; ++r) {
            int idx = tid + r * 256;
            int row = idx >> 2;
            int kc  = (idx & 3) << 3;
            *(uint4*)&Bs[row * LDAS + kc] =
                *(const uint4*)&Wt[(size_t)(bn + row) * K_DIM + k0 + kc];
        }
        __syncthreads();

        bf16x8 a[4], b[4];
        #pragma unroll
        for (int mt = 0; mt < 4; ++mt)
            a[mt] = *(const bf16x8*)&As[(wr * 64 + mt * 16 + mrow) * LDAS + kq];
        #pragma unroll
        for (int nt = 0; nt < 4; ++nt)
            b[nt] = *(const bf16x8*)&Bs[(wc * 64 + nt * 16 + mrow) * LDAS + kq];
        #pragma unroll
        for (int mt = 0; mt < 4; ++mt)
            #pragma unroll
            for (int nt = 0; nt < 4; ++nt)
                acc[mt][nt] = __builtin_amdgcn_mfma_f32_16x16x32_bf16(
                    a[mt], b[nt], acc[mt][nt], 0, 0, 0);
        __syncthreads();
    }

    // ---- epilogue: pair even/odd columns via shfl_xor(1); lane parity == col parity
    const bool isOdd = (mrow & 1);
    #pragma unroll
    for (int mt = 0; mt < 4; ++mt) {
        #pragma unroll
        for (int nt = 0; nt < 4; ++nt) {
            int gcol = bn + wc * 64 + nt * 16 + mrow;
            int o = gcol >> 1;
            float fb = sFB[o - obase];
            #pragma unroll
            for (int r = 0; r < 4; ++r) {
                float x = acc[mt][nt][r];
                float p = __shfl_xor(x, 1, 64);            // partner column's value
                float uo = isOdd ? x : p;                  // the odd-gate pre-act
                float f = 1.f / (1.f + __expf(-(uo + fb)));
                int grow = bm + wr * 64 + mt * 16 + (lane >> 4) * 4 + r;
                size_t oi = (size_t)grow * NOUT + o;
                if (isOdd) fbuf[oi]  = f;
                else       u0buf[oi] = x * (1.f - f);
            }
        }
    }
}

// ================= chunked scan (3 phases) ==================================
// Phase 1: per (col j, chunk c): compose chunk transform (F, U) with c_in = 0.
__global__ void scan_p1_kernel(const float* __restrict__ fgate,
                               const float* __restrict__ u0,     // cs buffer
                               float* __restrict__ Fbuf,
                               float* __restrict__ Ubuf) {
    int j  = blockIdx.x * 256 + threadIdx.x;   // column 0..NCOL-1
    int ch = blockIdx.y;                        // chunk 0..NCH-1
    size_t base = (size_t)ch * LC * NCOL + j;
    float F = 1.f, U = 0.f;
    #pragma unroll
    for (int l = 0; l < LC; ++l) {
        size_t idx = base + (size_t)l * NCOL;
        float ft = fgate[idx];
        float ut = u0[idx];
        U = fmaf(U, ft, ut);
        F = F * ft;
    }
    Fbuf[(size_t)ch * NCOL + j] = F;
    Ubuf[(size_t)ch * NCOL + j] = U;
}

// Phase 2: per col, sequentially combine NCH chunk transforms -> carry-ins.
__global__ void scan_p2_kernel(const float* __restrict__ Fbuf,
                               const float* __restrict__ Ubuf,
                               const float* __restrict__ c_init,
                               float* __restrict__ carry,
                               float* __restrict__ c_final) {
    int j = blockIdx.x * 256 + threadIdx.x;
    float c = c_init[j];
    #pragma unroll
    for (int ch = 0; ch < NCH; ++ch) {
        size_t ci = (size_t)ch * NCOL + j;
        carry[ci] = c;
        c = fmaf(Fbuf[ci], c, Ubuf[ci]);
    }
    c_final[j] = c;
}

// Phase 3: per (col, chunk): replay the exact FMA chain from carry-in, in-place.
__global__ void scan_p3_kernel(const float* __restrict__ fgate,
                               const float* __restrict__ carry,
                               float* __restrict__ cs) {          // holds u0
    int j  = blockIdx.x * 256 + threadIdx.x;
    int ch = blockIdx.y;
    size_t base = (size_t)ch * LC * NCOL + j;
    float c = carry[(size_t)ch * NCOL + j];
    #pragma unroll
    for (int l = 0; l < LC; ++l) {
        size_t idx = base + (size_t)l * NCOL;
        float ft = fgate[idx];
        float ut = cs[idx];
        c = fmaf(c, ft, ut);
        cs[idx] = c;
    }
}

// Fallback single-pass scan (only if ws too small for chunk buffers)
__global__ void scan_kernel(const float* __restrict__ fgate,
                            const float* __restrict__ c_init,
                            float* __restrict__ cs,
                            float* __restrict__ c_final) {
    int j = blockIdx.x * 256 + threadIdx.x;
    float c = c_init[j];
    #pragma unroll 4
    for (int l = 0; l < L_DIM; ++l) {
        size_t idx = (size_t)l * NCOL + j;
        float ft = fgate[idx];
        float u  = cs[idx];
        c = fmaf(c, ft, u);
        cs[idx] = c;
    }
    c_final[j] = c;
}

extern "C" void kernel_launch(void* const* d_in, const int* in_sizes, int n_in,
                              void* d_out, int out_size, void* d_ws, size_t ws_size,
                              hipStream_t stream) {
    const float* input  = (const float*)d_in[0];  // [L,B,NIN]
    const float* c_init = (const float*)d_in[1];  // [B,NOUT]
    const float* weight = (const float*)d_in[2];  // [NIN, 2*NOUT]
    const float* bias   = (const float*)d_in[3];  // [2*NOUT]

    float* out_cs = (float*)d_out;                         // [L,B,NOUT]
    float* out_cf = out_cs + (size_t)L_DIM * B_DIM * NOUT; // [B,NOUT]
    float* out_fg = out_cf + (size_t)B_DIM * NOUT;         // [L,B,NOUT]

    // ws layout: [Wt bf16 4MB][Abf bf16 64MB][F 4MB][U 4MB][carry 4MB]
    size_t wt_bytes = (size_t)N_DIM * K_DIM * sizeof(unsigned short);
    size_t wt_pad   = (wt_bytes + 255) & ~(size_t)255;
    size_t a_bytes  = (size_t)M_DIM * K_DIM * sizeof(unsigned short);
    size_t ch_bytes = (size_t)NCH * NCOL * sizeof(float);  // 4 MB each
    unsigned short* Wt  = (unsigned short*)d_ws;
    unsigned short* Abf = (unsigned short*)((char*)d_ws + wt_pad);
    bool pre_a = (ws_size >= wt_pad + a_bytes);
    size_t scan_off = pre_a ? (wt_pad + a_bytes) : wt_pad;
    float* Fbuf  = (float*)((char*)d_ws + scan_off);
    float* Ubuf  = Fbuf + NCH * NCOL;
    float* carry = Ubuf + NCH * NCOL;
    bool chunked = (ws_size >= scan_off + 3 * ch_bytes);

    // 1) weight fp32 [K][N] -> bf16 Wt [N][K]
    cvt_weight_kernel<<<dim3(N_DIM / 32, K_DIM / 32), dim3(32, 8), 0, stream>>>(weight, Wt);

    // 2) input fp32 -> bf16 (skippable fallback if ws too small)
    if (pre_a) {
        int nblk = (M_DIM * K_DIM) / (4 * 256);  // 32768
        cvt_input_kernel<<<nblk, 256, 0, stream>>>(input, Abf);
    }

    // 3) GEMM + gate epilogue: u0 -> out_cs (temp), forget -> out_fg
    dim3 ggrid(N_DIM / BN, M_DIM / BM);          // (16, 256)
    if (pre_a)
        gemm_kernel<true ><<<ggrid, 256, 0, stream>>>(input, Abf, Wt, bias, out_cs, out_fg);
    else
        gemm_kernel<false><<<ggrid, 256, 0, stream>>>(input, Abf, Wt, bias, out_cs, out_fg);

    // 4) recurrence: chunked 3-phase scan (falls back to single-pass if no ws)
    if (chunked) {
        dim3 sgrid(NCOL / 256, NCH);             // (64, 64)
        scan_p1_kernel<<<sgrid, 256, 0, stream>>>(out_fg, out_cs, Fbuf, Ubuf);
        scan_p2_kernel<<<NCOL / 256, 256, 0, stream>>>(Fbuf, Ubuf, c_init, carry, out_cf);
        scan_p3_kernel<<<sgrid, 256, 0, stream>>>(out_fg, carry, out_cs);
    } else {
        scan_kernel<<<NCOL / 256, 256, 0, stream>>>(out_fg, c_init, out_cs, out_cf);
    }
}